// Round 1
// baseline (137.948 us; speedup 1.0000x reference)
//
#include <hip/hip_runtime.h>
#include <math.h>

#define MM 63
#define NN 127
#define BB 256
#define NSH 4
#define STEP 31          // N // NUM_SHIFTS
#define NIT 3
#define RSTRIDE 65       // odd stride -> no LDS bank aliasing
#define CSTRIDE 49
#define NCHECK (3*NSH*MM)   // 756 check-instances per row-iteration

__device__ float g_partial[BB];

__global__ __launch_bounds__(1024)
void decode_kernel(const float* __restrict__ soft_in,
                   const int* __restrict__ labels,
                   const float* __restrict__ Hg,
                   const float* __restrict__ cw,
                   float* __restrict__ out)
{
    const int b   = blockIdx.x;
    const int tid = threadIdx.x;

    __shared__ int   row_cnt[MM];
    __shared__ int   row_idx[MM][RSTRIDE];
    __shared__ int   col_cnt[NN];
    __shared__ int   col_idx[NN][CSTRIDE];
    __shared__ float base[3][NN];     // base[0]=soft, [1]=split, [2]=perm
    __shared__ float tarr[3][NN];
    __shared__ float m1s[NCHECK], m2s[NCHECK], sgs[NCHECK];
    __shared__ float red[128];

    // ---- build CSR (check rows) and CSC (columns) of H, once per block ----
    if (tid < MM) {
        int cnt = 0;
        for (int n = 0; n < NN; ++n)
            if (Hg[tid*NN + n] != 0.0f) row_idx[tid][cnt++] = n;
        row_cnt[tid] = cnt;
    } else if (tid >= 64 && tid < 64 + NN) {
        int c = tid - 64, cnt = 0;
        for (int m = 0; m < MM; ++m)
            if (Hg[m*NN + c] != 0.0f) col_idx[c][cnt++] = m;
        col_cnt[c] = cnt;
    }
    // ---- load this block's soft row; emit outs[0] ----
    if (tid < NN) {
        float v = soft_in[b*NN + tid];
        base[0][tid] = v;
        out[b*NN + tid] = v;
    }
    const float spw = log1pf(expf(cw[0]));   // softplus(check_weight)
    __syncthreads();

    for (int it = 0; it < NIT; ++it) {
        // ---- build split / perm variants ----
        if (tid < NN) {
            base[1][tid] = (tid < 64) ? base[0][2*tid] : base[0][2*(tid-64)+1];
            base[2][tid] = base[0][(2*tid) % NN];
        }
        __syncthreads();

        // ---- Phase A: per (variant, shift, check): min1/min2/sign-product ----
        if (tid < NCHECK) {
            const int v   = tid / (NSH*MM);
            const int rem = tid - v*(NSH*MM);
            const int s   = rem / MM;
            const int m   = rem - s*MM;
            const int shift = s * STEP;
            const float* bp = base[v];
            const int cnt = row_cnt[m];
            float m1 = 3.4e38f, m2 = 3.4e38f, rs = 1.0f;
            for (int k = 0; k < cnt; ++k) {
                int c = row_idx[m][k];
                int idx = c - shift; if (idx < 0) idx += NN;   // roll(base, s)
                float x = bp[idx];
                float a = fminf(fabsf(x), 1e30f);
                float sg = (x > 0.0f) ? 1.0f : ((x < 0.0f) ? -1.0f : 0.0f);
                rs *= sg;
                if (a < m1) { m2 = m1; m1 = a; }
                else if (a < m2) { m2 = a; }
            }
            m1s[tid] = m1; m2s[tid] = m2; sgs[tid] = rs;
        }
        __syncthreads();

        // ---- Phase B: per (variant, final column n): gather via CSC ----
        // roll(temp, -s) folded into indexing: un-rolled position n always
        // corresponds to x = base_v[n]; the check column is j=(n+s)%N.
        if (tid < 3*NN) {
            const int v = tid / NN;
            const int n = tid - v*NN;
            float x  = base[v][n];
            float a  = fminf(fabsf(x), 1e30f);
            float sx = (x > 0.0f) ? 1.0f : ((x < 0.0f) ? -1.0f : 0.0f);
            float acc = 0.0f;
            #pragma unroll
            for (int s = 0; s < NSH; ++s) {
                int j = n + s*STEP; if (j >= NN) j -= NN;
                const int cc = col_cnt[j];
                const int sb = (v*NSH + s)*MM;
                for (int k = 0; k < cc; ++k) {
                    int m = col_idx[j][k];
                    float mv1 = m1s[sb+m];
                    float sel = (a > mv1) ? mv1 : m2s[sb+m];
                    acc += sel * sgs[sb+m];
                }
            }
            tarr[v][n] = spw * sx * acc;
        }
        __syncthreads();

        // ---- combine: t1 + un-split(t2) + un-perm(t3), update soft ----
        if (tid < NN) {
            const int n = tid;
            float i1 = (n & 1) ? tarr[1][64 + (n >> 1)] : tarr[1][n >> 1];
            float pp = tarr[2][(n * 64) % NN];     // INV[n] = 64n mod 127
            float ns = base[0][n] + (tarr[0][n] + i1 + pp) * (1.0f/12.0f);
            base[0][n] = ns;
            out[(size_t)(it+1)*(BB*NN) + b*NN + n] = ns;
        }
        __syncthreads();
    }

    // ---- per-row partial loss on final soft ----
    float term = 0.0f;
    if (tid < NN) {
        float sft = base[0][tid];
        float lf  = (float)labels[b*NN + tid];
        float sg  = (sft > 0.0f) ? 1.0f : ((sft < 0.0f) ? -1.0f : 0.0f);
        float w   = (sg != (1.0f - 2.0f*lf)) ? 2.0f : 1.0f;
        float z   = -sft;
        float ce  = fmaxf(z, 0.0f) - z*lf + log1pf(expf(-fabsf(z)));
        term = w * ce;
    }
    if (tid < 128) red[tid] = term;
    __syncthreads();
    #pragma unroll
    for (int off = 64; off > 0; off >>= 1) {
        if (tid < off) red[tid] += red[tid + off];
        __syncthreads();
    }
    if (tid == 0) g_partial[b] = red[0];
}

__global__ __launch_bounds__(256)
void loss_kernel(float* __restrict__ out)
{
    __shared__ float red[256];
    const int tid = threadIdx.x;
    red[tid] = g_partial[tid];
    __syncthreads();
    for (int off = 128; off > 0; off >>= 1) {
        if (tid < off) red[tid] += red[tid + off];
        __syncthreads();
    }
    if (tid == 0) out[4*BB*NN] = red[0];   // loss slot
}

extern "C" void kernel_launch(void* const* d_in, const int* in_sizes, int n_in,
                              void* d_out, int out_size, void* d_ws, size_t ws_size,
                              hipStream_t stream) {
    const float* soft   = (const float*)d_in[0];
    const int*   labels = (const int*)  d_in[1];
    const float* H      = (const float*)d_in[2];
    const float* cw     = (const float*)d_in[3];
    float* out = (float*)d_out;

    decode_kernel<<<BB, 1024, 0, stream>>>(soft, labels, H, cw, out);
    loss_kernel<<<1, 256, 0, stream>>>(out);
}

// Round 2
// 119.121 us; speedup vs baseline: 1.1581x; 1.1581x over previous
//
#include <hip/hip_runtime.h>
#include <math.h>

#define MM 63
#define NN 127
#define BB 256
#define NSH 4
#define STEP 31           // N / NUM_SHIFTS
#define NIT 3
#define RSTRIDE 68        // max row support (<=65 proven) padded to mult-of-4
#define CSTRIDE 52        // max col support (<=49 proven) padded to mult-of-4
#define NTHREADS 768      // 12 waves: exactly covers 12 (v,s) groups in Phase A

__device__ float g_partial[BB];

__global__ __launch_bounds__(NTHREADS)
void decode_kernel(const float* __restrict__ soft_in,
                   const int* __restrict__ labels,
                   const float* __restrict__ Hg,
                   const float* __restrict__ cw,
                   float* __restrict__ out)
{
    const int b   = blockIdx.x;
    const int tid = threadIdx.x;

    __shared__ int    row_cnt[MM];
    __shared__ int    row_idx[MM][RSTRIDE];
    __shared__ int    col_cnt[NN];
    __shared__ int    col_idx[NN][CSTRIDE];
    __shared__ float  base0[NN + 1];       // slot 127 = +1e30 sentinel
    __shared__ float  tarr[3][NN];
    __shared__ float2 pq[12 * 64];         // (v*4+s)*64 + m ; m==63 is zero slot
    __shared__ float  red[12];

    // ---------------- build CSR / CSC of H (once per block) ----------------
    if (tid < MM) {
        int cnt = 0;
        for (int n = 0; n < NN; ++n)
            if (Hg[tid * NN + n] != 0.0f) row_idx[tid][cnt++] = n;
        while (cnt & 3) row_idx[tid][cnt++] = 255;       // sentinel column
        row_cnt[tid] = cnt;
    } else if (tid >= 64 && tid < 64 + NN) {
        int c = tid - 64, cnt = 0;
        for (int m = 0; m < MM; ++m)
            if (Hg[m * NN + c] != 0.0f) col_idx[c][cnt++] = m;
        while (cnt & 3) col_idx[c][cnt++] = 63;          // sentinel check
        col_cnt[c] = cnt;
    } else if (tid >= 192 && tid < 204) {
        pq[(tid - 192) * 64 + 63] = make_float2(0.0f, 0.0f);  // zero slots
        if (tid == 192) base0[NN] = 1e30f;
    }
    if (tid < NN) {
        float v = soft_in[b * NN + tid];
        base0[tid] = v;
        out[b * NN + tid] = v;               // outs[0]
    }
    const float spw = log1pf(expf(cw[0]));   // softplus(check_weight)
    __syncthreads();

    for (int it = 0; it < NIT; ++it) {
        // ---- Phase A: (v,s,m) -> (p,q) = rs*(min1,min2); wave-uniform v,s ----
        {
            const int m  = tid & 63;
            const int vs = tid >> 6;         // 0..11
            if (m < MM) {
                const int v = vs >> 2;
                const int shift = (vs & 3) * STEP;
                const int cnt = row_cnt[m];
                float m1 = 3.4e38f, m2 = 3.4e38f, rs = 1.0f;
                for (int k = 0; k < cnt; k += 4) {
                    int c0 = row_idx[m][k + 0];
                    int c1 = row_idx[m][k + 1];
                    int c2 = row_idx[m][k + 2];
                    int c3 = row_idx[m][k + 3];
                    #define MAPIDX(c, h)                                   \
                        { int idx = (c) - shift; idx += (idx < 0) ? NN : 0;\
                          if (v == 0)      h = idx;                        \
                          else if (v == 1) h = (idx < 64) ? 2*idx : 2*(idx-64)+1; \
                          else { h = 2*idx; h -= (h >= NN) ? NN : 0; }     \
                          h = ((c) == 255) ? NN : h; }
                    int h0, h1, h2, h3;
                    MAPIDX(c0, h0) MAPIDX(c1, h1) MAPIDX(c2, h2) MAPIDX(c3, h3)
                    #undef MAPIDX
                    float x0 = base0[h0], x1 = base0[h1];
                    float x2 = base0[h2], x3 = base0[h3];
                    #define PROC(x)                                        \
                        { float a = fminf(fabsf(x), 1e30f);                \
                          float sg = ((x) > 0.f) ? 1.f : (((x) < 0.f) ? -1.f : 0.f); \
                          rs *= sg;                                        \
                          if (a < m1) { m2 = m1; m1 = a; }                 \
                          else if (a < m2) { m2 = a; } }
                    PROC(x0) PROC(x1) PROC(x2) PROC(x3)
                    #undef PROC
                }
                pq[vs * 64 + m] = make_float2(rs * m1, rs * m2);
            }
        }
        __syncthreads();

        // ---- Phase B: 2 threads per (v,n), 2 shifts each, shfl combine ----
        if (tid < 762) {
            const int task = tid >> 1;       // 0..380
            const int half = tid & 1;
            const int v = task / NN;
            const int n = task - v * NN;
            int gn;
            if (v == 0)      gn = n;
            else if (v == 1) gn = (n < 64) ? 2*n : 2*(n-64)+1;
            else { gn = 2*n; gn -= (gn >= NN) ? NN : 0; }
            const float x  = base0[gn];
            const float a  = fminf(fabsf(x), 1e30f);
            const float sx = (x > 0.f) ? 1.f : ((x < 0.f) ? -1.f : 0.f);
            float acc = 0.0f;
            #pragma unroll
            for (int ds = 0; ds < 2; ++ds) {
                const int s = half * 2 + ds;
                int j = n + s * STEP; j -= (j >= NN) ? NN : 0;
                const int cc = col_cnt[j];
                const float2* pqs = &pq[(v * NSH + s) * 64];
                for (int k = 0; k < cc; k += 4) {
                    int m0 = col_idx[j][k + 0];
                    int m1i = col_idx[j][k + 1];
                    int m2i = col_idx[j][k + 2];
                    int m3 = col_idx[j][k + 3];
                    float2 e0 = pqs[m0], e1 = pqs[m1i];
                    float2 e2 = pqs[m2i], e3 = pqs[m3];
                    acc += (a > fabsf(e0.x)) ? e0.x : e0.y;
                    acc += (a > fabsf(e1.x)) ? e1.x : e1.y;
                    acc += (a > fabsf(e2.x)) ? e2.x : e2.y;
                    acc += (a > fabsf(e3.x)) ? e3.x : e3.y;
                }
            }
            acc += __shfl_xor(acc, 1);
            if (half == 0) tarr[v][n] = spw * sx * acc;
        }
        __syncthreads();

        // ---- combine: soft += (t1 + unsplit(t2) + unperm(t3)) / 12 ----
        if (tid < NN) {
            const int n = tid;
            float i1 = (n & 1) ? tarr[1][64 + (n >> 1)] : tarr[1][n >> 1];
            float pp = tarr[2][(n * 64) % NN];          // INV[n] = 64n mod 127
            float ns = base0[n] + (tarr[0][n] + i1 + pp) * (1.0f / 12.0f);
            base0[n] = ns;
            out[(size_t)(it + 1) * (BB * NN) + b * NN + n] = ns;
        }
        __syncthreads();
    }

    // ---------------- per-row loss on final soft ----------------
    float term = 0.0f;
    if (tid < NN) {
        float sft = base0[tid];
        float lf  = (float)labels[b * NN + tid];
        float sg  = (sft > 0.f) ? 1.f : ((sft < 0.f) ? -1.f : 0.f);
        float w   = (sg != (1.0f - 2.0f * lf)) ? 2.0f : 1.0f;
        float z   = -sft;
        term = w * (fmaxf(z, 0.f) - z * lf + log1pf(expf(-fabsf(z))));
    }
    #pragma unroll
    for (int off = 32; off > 0; off >>= 1)
        term += __shfl_down(term, off);
    if ((tid & 63) == 0) red[tid >> 6] = term;
    __syncthreads();
    if (tid == 0) {
        float s = 0.0f;
        #pragma unroll
        for (int w = 0; w < 12; ++w) s += red[w];
        g_partial[b] = s;
    }
}

__global__ __launch_bounds__(256)
void loss_kernel(float* __restrict__ out)
{
    __shared__ float red[256];
    const int tid = threadIdx.x;
    red[tid] = g_partial[tid];
    __syncthreads();
    for (int off = 128; off > 0; off >>= 1) {
        if (tid < off) red[tid] += red[tid + off];
        __syncthreads();
    }
    if (tid == 0) out[4 * BB * NN] = red[0];   // loss slot
}

extern "C" void kernel_launch(void* const* d_in, const int* in_sizes, int n_in,
                              void* d_out, int out_size, void* d_ws, size_t ws_size,
                              hipStream_t stream) {
    const float* soft   = (const float*)d_in[0];
    const int*   labels = (const int*)  d_in[1];
    const float* H      = (const float*)d_in[2];
    const float* cw     = (const float*)d_in[3];
    float* outp = (float*)d_out;

    decode_kernel<<<BB, NTHREADS, 0, stream>>>(soft, labels, H, cw, outp);
    loss_kernel<<<1, 256, 0, stream>>>(outp);
}

// Round 3
// 86.243 us; speedup vs baseline: 1.5995x; 1.3812x over previous
//
#include <hip/hip_runtime.h>
#include <math.h>

#define MM 63
#define NN 127
#define BB 256
#define NIT 3
#define CSR_STRIDE 76      // bytes per check row list (19 words, odd)
#define CSC_STRIDE 44      // bytes per column list (11 words, odd)
#define PQ_STRIDE 65       // float2 slots per (v,s) group (odd)

__device__ float g_partial[BB];

__global__ __launch_bounds__(1024)
void decode_kernel(const float* __restrict__ soft_in,
                   const int* __restrict__ labels,
                   const float* __restrict__ Hg,
                   const float* __restrict__ cw,
                   float* __restrict__ out)
{
    const int b    = blockIdx.x;
    const int tid  = threadIdx.x;
    const int lane = tid & 63;
    const int wid  = tid >> 6;

    __shared__ unsigned char csr[MM][CSR_STRIDE];
    __shared__ unsigned char csc[NN][CSC_STRIDE];
    __shared__ int   row_w2[MM];          // ceil(cnt/8): packed words per half
    __shared__ int   col_w[NN];           // ceil(cnt/4): packed words
    __shared__ float base0[NN + 1];       // [127] = +1e30 sentinel
    __shared__ float2 pq[8 * PQ_STRIDE];  // (v*4+s)*65 + m ; m==63 zero slot
    __shared__ float tarr[2][NN];
    __shared__ float red2[2];

    // ---- parallel CSR/CSC build: one wave per H row / column (ballot) ----
    for (int task = wid; task < MM + NN; task += 16) {
        unsigned long long below = (1ull << lane) - 1ull;
        if (task < MM) {
            const int m = task;
            csr[m][lane] = 127;                               // sentinel fill
            if (lane < CSR_STRIDE - 64) csr[m][64 + lane] = 127;
            float h0 = Hg[m * NN + lane];
            float h1 = (lane < NN - 64) ? Hg[m * NN + 64 + lane] : 0.0f;
            unsigned long long b0 = __ballot(h0 != 0.0f);
            unsigned long long b1 = __ballot(h1 != 0.0f);
            int c0 = __popcll(b0);
            if (h0 != 0.0f) csr[m][__popcll(b0 & below)] = (unsigned char)lane;
            if (h1 != 0.0f) csr[m][c0 + __popcll(b1 & below)] = (unsigned char)(64 + lane);
            if (lane == 0) row_w2[m] = (c0 + __popcll(b1) + 7) >> 3;
        } else {
            const int c = task - MM;
            if (lane < CSC_STRIDE) csc[c][lane] = 63;         // sentinel fill
            float hv = (lane < MM) ? Hg[lane * NN + c] : 0.0f;
            unsigned long long bm = __ballot(hv != 0.0f);
            if (hv != 0.0f) csc[c][__popcll(bm & below)] = (unsigned char)lane;
            if (lane == 0) col_w[c] = (__popcll(bm) + 3) >> 2;
        }
    }
    if (tid < NN) {
        float v = soft_in[b * NN + tid];
        base0[tid] = v;
        out[b * NN + tid] = v;                                // outs[0]
    }
    if (tid == NN) base0[NN] = 1e30f;
    if (tid >= 256 && tid < 264)                              // pq zero slots
        pq[(tid - 256) * PQ_STRIDE + 63] = make_float2(0.0f, 0.0f);
    const float spw = log1pf(expf(cw[0]));                    // softplus
    __syncthreads();

    for (int it = 0; it < NIT; ++it) {
        // ---- Phase A: 2 threads per (vs, check m); half-row each ----
        {
            const int vs    = tid >> 7;          // 0..7 (v = vs>>2, s = vs&3)
            const int mslot = (tid >> 1) & 63;
            const int half  = tid & 1;
            if (mslot < MM) {
                const int v     = vs >> 2;
                const int shift = (vs & 3) * 31;
                const int H2    = row_w2[mslot];
                const unsigned int* wp = (const unsigned int*)&csr[mslot][0];
                float m1 = 1e30f, m2 = 1e30f;
                unsigned int sbits = 0u;
                for (int w = half * H2, e = 0; e < H2; ++e, ++w) {
                    unsigned int pk = wp[w];
                    #pragma unroll
                    for (int j = 0; j < 4; ++j) {
                        int c = (pk >> (8 * j)) & 255;
                        int idx = c - shift; idx += (idx < 0) ? NN : 0;   // roll
                        if (v) { idx <<= 1; idx -= (idx >= NN) ? NN : 0; } // perm
                        idx = (c == 127) ? 127 : idx;                     // sentinel
                        float x = base0[idx];
                        float a = fminf(fabsf(x), 1e30f);
                        sbits ^= __float_as_uint(x);
                        m2 = fminf(m2, fmaxf(a, m1));
                        m1 = fminf(m1, a);
                    }
                }
                float om1 = __shfl_xor(m1, 1);
                float om2 = __shfl_xor(m2, 1);
                unsigned int osb = (unsigned int)__shfl_xor((int)sbits, 1);
                float mm2 = fminf(fminf(m2, om2), fmaxf(m1, om1));
                float mm1 = fminf(m1, om1);
                sbits ^= osb;
                float rs = (sbits >> 31) ? -1.0f : 1.0f;
                rs = (mm1 == 0.0f) ? 0.0f : rs;
                if (half == 0)
                    pq[vs * PQ_STRIDE + mslot] = make_float2(rs * mm1, rs * mm2);
            }
        }
        __syncthreads();

        // ---- Phase B: 4 threads per (v, n); one shift each ----
        {
            const int v = tid >> 9;              // 0,1
            const int n = (tid >> 2) & 127;
            const int s = tid & 3;
            if (n < NN) {
                int gn = n;
                if (v) { gn <<= 1; gn -= (gn >= NN) ? NN : 0; }
                const float x = base0[gn];
                const float a = fminf(fabsf(x), 1e30f);
                int jcol = n + s * 31; jcol -= (jcol >= NN) ? NN : 0;
                const int C2 = col_w[jcol];
                const unsigned int* wp = (const unsigned int*)&csc[jcol][0];
                const float2* pqs = &pq[((v << 2) | s) * PQ_STRIDE];
                float acc = 0.0f;
                for (int w = 0; w < C2; ++w) {
                    unsigned int pk = wp[w];
                    #pragma unroll
                    for (int e = 0; e < 4; ++e) {
                        int m = (pk >> (8 * e)) & 255;
                        float2 pv = pqs[m];
                        acc += (a > fabsf(pv.x)) ? pv.x : pv.y;
                    }
                }
                acc += __shfl_xor(acc, 1);
                acc += __shfl_xor(acc, 2);
                if (s == 0) {
                    float sx = (x > 0.0f) ? 1.0f : ((x < 0.0f) ? -1.0f : 0.0f);
                    tarr[v][n] = spw * sx * acc;
                }
            }
        }
        __syncthreads();

        // ---- combine: soft += (t1[n] + 2*t2[(64n)%127]) / 12 ----
        if (tid < NN) {
            const int n = tid;
            float t2v = tarr[1][(n * 64) % NN];
            float ns = base0[n] + (tarr[0][n] + 2.0f * t2v) * (1.0f / 12.0f);
            base0[n] = ns;
            out[(size_t)(it + 1) * (BB * NN) + b * NN + n] = ns;
        }
        __syncthreads();
    }

    // ---- per-row loss on final soft ----
    float term = 0.0f;
    if (tid < NN) {
        float sft = base0[tid];
        float lf  = (float)labels[b * NN + tid];
        float sg  = (sft > 0.0f) ? 1.0f : ((sft < 0.0f) ? -1.0f : 0.0f);
        float w   = (sg != (1.0f - 2.0f * lf)) ? 2.0f : 1.0f;
        float z   = -sft;
        term = w * (fmaxf(z, 0.0f) - z * lf + log1pf(expf(-fabsf(z))));
    }
    if (tid < 128) {
        #pragma unroll
        for (int off = 32; off > 0; off >>= 1)
            term += __shfl_down(term, off);
        if (lane == 0) red2[wid] = term;
    }
    __syncthreads();
    if (tid == 0) g_partial[b] = red2[0] + red2[1];
}

__global__ __launch_bounds__(256)
void loss_kernel(float* __restrict__ out)
{
    __shared__ float red[256];
    const int tid = threadIdx.x;
    red[tid] = g_partial[tid];
    __syncthreads();
    for (int off = 128; off > 0; off >>= 1) {
        if (tid < off) red[tid] += red[tid + off];
        __syncthreads();
    }
    if (tid == 0) out[4 * BB * NN] = red[0];   // loss slot
}

extern "C" void kernel_launch(void* const* d_in, const int* in_sizes, int n_in,
                              void* d_out, int out_size, void* d_ws, size_t ws_size,
                              hipStream_t stream) {
    const float* soft   = (const float*)d_in[0];
    const int*   labels = (const int*)  d_in[1];
    const float* H      = (const float*)d_in[2];
    const float* cw     = (const float*)d_in[3];
    float* outp = (float*)d_out;

    decode_kernel<<<BB, 1024, 0, stream>>>(soft, labels, H, cw, outp);
    loss_kernel<<<1, 256, 0, stream>>>(outp);
}